// Round 4
// baseline (1251.895 us; speedup 1.0000x reference)
//
#include <hip/hip_runtime.h>
#include <hip/hip_bf16.h>

#define HIDDEN 256
#define IN_CH 128

// ---------------- degree (generic over an index array) ----------------
__global__ void k_deg(const int* __restrict__ idx, int* __restrict__ deg, int E) {
    int e = blockIdx.x * blockDim.x + threadIdx.x;
    if (e < E) atomicAdd(&deg[idx[e]], 1);
}

__global__ void k_dinv(const int* __restrict__ deg, float* __restrict__ dinv, int N) {
    int n = blockIdx.x * blockDim.x + threadIdx.x;
    if (n < N) dinv[n] = rsqrtf((float)deg[n] + 1.0f);  // +1 self loop
}

// ---------------- hierarchical exclusive prefix scan of deg -> offs ----------------
__global__ void k_chunksum(const int* __restrict__ deg, int* __restrict__ part, int N) {
    __shared__ int sh[256];
    int i = blockIdx.x * 256 + threadIdx.x;
    sh[threadIdx.x] = (i < N) ? deg[i] : 0;
    __syncthreads();
    for (int st = 128; st > 0; st >>= 1) {
        if (threadIdx.x < st) sh[threadIdx.x] += sh[threadIdx.x + st];
        __syncthreads();
    }
    if (threadIdx.x == 0) part[blockIdx.x] = sh[0];
}

__global__ void k_scanpart(int* __restrict__ part, int nb) {
    __shared__ int sh[256];
    int v = (threadIdx.x < nb) ? part[threadIdx.x] : 0;
    sh[threadIdx.x] = v;
    __syncthreads();
    for (int st = 1; st < 256; st <<= 1) {
        int t = (threadIdx.x >= st) ? sh[threadIdx.x - st] : 0;
        __syncthreads();
        sh[threadIdx.x] += t;
        __syncthreads();
    }
    if (threadIdx.x < nb) part[threadIdx.x] = sh[threadIdx.x] - v;
}

__global__ void k_scanfinal(const int* __restrict__ deg, const int* __restrict__ part,
                            int* __restrict__ offs, int N, int E) {
    __shared__ int sh[256];
    int i = blockIdx.x * 256 + threadIdx.x;
    int v = (i < N) ? deg[i] : 0;
    sh[threadIdx.x] = v;
    __syncthreads();
    for (int st = 1; st < 256; st <<= 1) {
        int t = (threadIdx.x >= st) ? sh[threadIdx.x - st] : 0;
        __syncthreads();
        sh[threadIdx.x] += t;
        __syncthreads();
    }
    if (i < N) offs[i] = part[blockIdx.x] + sh[threadIdx.x] - v;
    if (i == 0) offs[N] = E;
}

// ---------------- counting-sort scatter: payload grouped by key ----------------
__global__ void k_scatter(const int* __restrict__ pay, const int* __restrict__ key,
                          const int* __restrict__ offs, int* __restrict__ cursor,
                          int* __restrict__ spay, int E) {
    int e = blockIdx.x * blockDim.x + threadIdx.x;
    if (e >= E) return;
    int d = key[e];
    int p = offs[d] + atomicAdd(&cursor[d], 1);
    spay[p] = pay[e];
}

// scatter with two payloads (dst + edge id), grouped by src
__global__ void k_scatter2(const int* __restrict__ key, const int* __restrict__ pay,
                           const int* __restrict__ offs, int* __restrict__ cursor,
                           int* __restrict__ spay, int* __restrict__ seid, int E) {
    int e = blockIdx.x * blockDim.x + threadIdx.x;
    if (e >= E) return;
    int s = key[e];
    int p = offs[s] + atomicAdd(&cursor[s], 1);
    spay[p] = pay[e];
    seid[p] = e;
}

// ---------------- register-blocked GEMM: C[M,256] = (A[M,K]@W[K,256]+bias)*rowscale? ----------------
template<int K>
__global__ __launch_bounds__(256) void k_gemm64(const float* __restrict__ A,
        const float* __restrict__ W, const float* __restrict__ bias,
        const float* __restrict__ rowscale, float* __restrict__ C, int M) {
    __shared__ float As[32 * 64];   // [k][m]
    __shared__ float Bs[32 * 256];  // [k][n]
    const int tid = threadIdx.x;
    const int tc = tid & 63;
    const int tr = tid >> 6;
    const int m0 = blockIdx.x * 64;
    const int rows = (M - m0 < 64) ? (M - m0) : 64;

    float acc[16][4];
#pragma unroll
    for (int r = 0; r < 16; ++r)
#pragma unroll
        for (int c = 0; c < 4; ++c) acc[r][c] = 0.f;

    const int arow = tid & 63;
    const int akq = tid >> 6;
    float4* As4 = reinterpret_cast<float4*>(As);
    float4* Bs4 = reinterpret_cast<float4*>(Bs);

    for (int kc = 0; kc < K; kc += 32) {
        __syncthreads();
#pragma unroll
        for (int it = 0; it < 2; ++it) {
            int kq = akq + it * 4;
            float4 v = make_float4(0.f, 0.f, 0.f, 0.f);
            if (arow < rows)
                v = *reinterpret_cast<const float4*>(A + (size_t)(m0 + arow) * K + kc + kq * 4);
            As[(kq * 4 + 0) * 64 + arow] = v.x;
            As[(kq * 4 + 1) * 64 + arow] = v.y;
            As[(kq * 4 + 2) * 64 + arow] = v.z;
            As[(kq * 4 + 3) * 64 + arow] = v.w;
        }
        const float4* W4 = reinterpret_cast<const float4*>(W + (size_t)kc * 256);
#pragma unroll
        for (int it = 0; it < 8; ++it)
            Bs4[tid + it * 256] = W4[tid + it * 256];
        __syncthreads();
#pragma unroll 8
        for (int kk = 0; kk < 32; ++kk) {
            float4 b = Bs4[kk * 64 + tc];
#pragma unroll
            for (int u = 0; u < 4; ++u) {
                float4 a = As4[kk * 16 + tr * 4 + u];
                acc[u * 4 + 0][0] = fmaf(a.x, b.x, acc[u * 4 + 0][0]);
                acc[u * 4 + 0][1] = fmaf(a.x, b.y, acc[u * 4 + 0][1]);
                acc[u * 4 + 0][2] = fmaf(a.x, b.z, acc[u * 4 + 0][2]);
                acc[u * 4 + 0][3] = fmaf(a.x, b.w, acc[u * 4 + 0][3]);
                acc[u * 4 + 1][0] = fmaf(a.y, b.x, acc[u * 4 + 1][0]);
                acc[u * 4 + 1][1] = fmaf(a.y, b.y, acc[u * 4 + 1][1]);
                acc[u * 4 + 1][2] = fmaf(a.y, b.z, acc[u * 4 + 1][2]);
                acc[u * 4 + 1][3] = fmaf(a.y, b.w, acc[u * 4 + 1][3]);
                acc[u * 4 + 2][0] = fmaf(a.z, b.x, acc[u * 4 + 2][0]);
                acc[u * 4 + 2][1] = fmaf(a.z, b.y, acc[u * 4 + 2][1]);
                acc[u * 4 + 2][2] = fmaf(a.z, b.z, acc[u * 4 + 2][2]);
                acc[u * 4 + 2][3] = fmaf(a.z, b.w, acc[u * 4 + 2][3]);
                acc[u * 4 + 3][0] = fmaf(a.w, b.x, acc[u * 4 + 3][0]);
                acc[u * 4 + 3][1] = fmaf(a.w, b.y, acc[u * 4 + 3][1]);
                acc[u * 4 + 3][2] = fmaf(a.w, b.z, acc[u * 4 + 3][2]);
                acc[u * 4 + 3][3] = fmaf(a.w, b.w, acc[u * 4 + 3][3]);
            }
        }
    }

    float4 bv = *reinterpret_cast<const float4*>(bias + tc * 4);
#pragma unroll
    for (int r = 0; r < 16; ++r) {
        int lrow = tr * 16 + r;
        if (lrow < rows) {
            float4 v;
            v.x = acc[r][0] + bv.x;
            v.y = acc[r][1] + bv.y;
            v.z = acc[r][2] + bv.z;
            v.w = acc[r][3] + bv.w;
            if (rowscale) {
                float s = rowscale[m0 + lrow];
                v.x *= s; v.y *= s; v.z *= s; v.w *= s;
            }
            *reinterpret_cast<float4*>(C + (size_t)(m0 + lrow) * 256 + tc * 4) = v;
        }
    }
}

// ---------------- gather aggregation, 16-deep load pipeline ----------------
__global__ __launch_bounds__(256) void k_gather_agg(const float* __restrict__ Ys,
        const int* __restrict__ offs, const int* __restrict__ ssrc,
        const float* __restrict__ dinv, float* __restrict__ outp, int N, int relu) {
    int wid = threadIdx.x >> 6, lane = threadIdx.x & 63;
    int d = blockIdx.x * 4 + wid;
    if (d >= N) return;
    int beg = offs[d], end = offs[d + 1];
    float4 acc = reinterpret_cast<const float4*>(Ys + (size_t)d * 256)[lane];  // self loop
    int i = beg;
    for (; i + 16 <= end; i += 16) {
        int sIdx[16];
#pragma unroll
        for (int u = 0; u < 16; ++u) sIdx[u] = ssrc[i + u];
        float4 v[16];
#pragma unroll
        for (int u = 0; u < 16; ++u)
            v[u] = reinterpret_cast<const float4*>(Ys + (size_t)sIdx[u] * 256)[lane];
#pragma unroll
        for (int u = 0; u < 16; ++u) {
            acc.x += v[u].x; acc.y += v[u].y; acc.z += v[u].z; acc.w += v[u].w;
        }
    }
    for (; i + 4 <= end; i += 4) {
        int s0 = ssrc[i], s1 = ssrc[i + 1], s2 = ssrc[i + 2], s3 = ssrc[i + 3];
        float4 v0 = reinterpret_cast<const float4*>(Ys + (size_t)s0 * 256)[lane];
        float4 v1 = reinterpret_cast<const float4*>(Ys + (size_t)s1 * 256)[lane];
        float4 v2 = reinterpret_cast<const float4*>(Ys + (size_t)s2 * 256)[lane];
        float4 v3 = reinterpret_cast<const float4*>(Ys + (size_t)s3 * 256)[lane];
        acc.x += (v0.x + v1.x) + (v2.x + v3.x);
        acc.y += (v0.y + v1.y) + (v2.y + v3.y);
        acc.z += (v0.z + v1.z) + (v2.z + v3.z);
        acc.w += (v0.w + v1.w) + (v2.w + v3.w);
    }
    for (; i < end; ++i) {
        int s = ssrc[i];
        float4 v = reinterpret_cast<const float4*>(Ys + (size_t)s * 256)[lane];
        acc.x += v.x; acc.y += v.y; acc.z += v.z; acc.w += v.w;
    }
    float sc = dinv[d];
    acc.x *= sc; acc.y *= sc; acc.z *= sc; acc.w *= sc;
    if (relu) {
        acc.x = fmaxf(acc.x, 0.f); acc.y = fmaxf(acc.y, 0.f);
        acc.z = fmaxf(acc.z, 0.f); acc.w = fmaxf(acc.w, 0.f);
    }
    reinterpret_cast<float4*>(outp + (size_t)d * 256)[lane] = acc;
}

// ---------------- transpose 256x256 ----------------
__global__ void k_transpose256(const float* __restrict__ Win, float* __restrict__ Wout) {
    int j = threadIdx.x, k = blockIdx.x;
    Wout[k * 256 + j] = Win[j * 256 + k];
}

// ---------------- wsum / bsum ----------------
__global__ void k_wsum(const float* __restrict__ opw, const float* __restrict__ opb,
                       float* __restrict__ wsum, float* __restrict__ bsum) {
    int c = threadIdx.x;
    float s = 0.f;
    for (int j = 0; j < 256; ++j) s += opw[j * 256 + c];
    wsum[c] = s;
    __shared__ float red[256];
    red[c] = opb[c];
    __syncthreads();
    for (int st = 128; st > 0; st >>= 1) {
        if (c < st) red[c] += red[c + st];
        __syncthreads();
    }
    if (c == 0) *bsum = red[0];
}

// ---------------- wv_eff ----------------
__global__ void k_wveff(const float* __restrict__ ipw, const float* __restrict__ ipb,
                        const float* __restrict__ wsum, float* __restrict__ wv_eff,
                        float* __restrict__ vconst) {
    int h = blockIdx.x, k = threadIdx.x;
    float s = 0.f;
    for (int c = 0; c < 64; ++c)
        s += wsum[h * 64 + c] * ipw[(size_t)(512 + h * 64 + c) * 256 + k];
    wv_eff[h * 256 + k] = s;
    if (k == 0) {
        float t = 0.f;
        for (int c = 0; c < 64; ++c) t += ipb[512 + h * 64 + c] * wsum[h * 64 + c];
        vconst[h] = t;
    }
}

// ---------------- per-node: qk_self[n][h], vw[n][h] ----------------
__global__ void k_node_aux(const float* __restrict__ Q, const float* __restrict__ Km,
                           const float* __restrict__ Z, const float* __restrict__ wv_eff,
                           const float* __restrict__ vconst,
                           float* __restrict__ qk_self, float* __restrict__ vw, int N) {
    int wid = threadIdx.x >> 6, lane = threadIdx.x & 63;
    int n = blockIdx.x * 4 + wid;
    if (n >= N) return;
    float4 q = reinterpret_cast<const float4*>(Q + (size_t)n * 256)[lane];
    float4 k = reinterpret_cast<const float4*>(Km + (size_t)n * 256)[lane];
    float4 z = reinterpret_cast<const float4*>(Z + (size_t)n * 256)[lane];
    float p = q.x * k.x + q.y * k.y + q.z * k.z + q.w * k.w;
    for (int st = 1; st < 16; st <<= 1) p += __shfl_xor(p, st);
    if ((lane & 15) == 0) qk_self[n * 4 + (lane >> 4)] = p;

    float ph0, ph1, ph2, ph3;
    {
        float4 w;
        w = reinterpret_cast<const float4*>(wv_eff + 0 * 256)[lane];
        ph0 = z.x * w.x + z.y * w.y + z.z * w.z + z.w * w.w;
        w = reinterpret_cast<const float4*>(wv_eff + 1 * 256)[lane];
        ph1 = z.x * w.x + z.y * w.y + z.z * w.z + z.w * w.w;
        w = reinterpret_cast<const float4*>(wv_eff + 2 * 256)[lane];
        ph2 = z.x * w.x + z.y * w.y + z.z * w.z + z.w * w.w;
        w = reinterpret_cast<const float4*>(wv_eff + 3 * 256)[lane];
        ph3 = z.x * w.x + z.y * w.y + z.z * w.z + z.w * w.w;
    }
    for (int st = 1; st < 64; st <<= 1) {
        ph0 += __shfl_xor(ph0, st);
        ph1 += __shfl_xor(ph1, st);
        ph2 += __shfl_xor(ph2, st);
        ph3 += __shfl_xor(ph3, st);
    }
    if (lane == 0) {
        vw[n * 4 + 0] = ph0 + vconst[0];
        vw[n * 4 + 1] = ph1 + vconst[1];
        vw[n * 4 + 2] = ph2 + vconst[2];
        vw[n * 4 + 3] = ph3 + vconst[3];
    }
}

// ---------------- per pred-edge final, grouped by source ----------------
__global__ __launch_bounds__(256) void k_edge_pred_grouped(const float* __restrict__ Q,
        const float* __restrict__ Km, const float* __restrict__ qk_self,
        const float* __restrict__ vw, const float* __restrict__ bsum,
        const int* __restrict__ offs_p, const int* __restrict__ sdst,
        const int* __restrict__ seid, float* __restrict__ out, int N) {
    int wid = threadIdx.x >> 6, lane = threadIdx.x & 63;
    int s = blockIdx.x * 4 + wid;
    if (s >= N) return;
    int beg = offs_p[s], end = offs_p[s + 1];
    if (beg == end) return;
    float4 q = reinterpret_cast<const float4*>(Q + (size_t)s * 256)[lane];
    int h = lane >> 4;
    const float scale = 0.125f;
    float s0 = qk_self[s * 4 + h] * scale;
    float vs = vw[s * 4 + h];
    float bs = *bsum;

    int i = beg;
    for (; i + 2 <= end; i += 2) {
        int d0 = sdst[i], d1 = sdst[i + 1];
        float4 k0 = reinterpret_cast<const float4*>(Km + (size_t)d0 * 256)[lane];
        float4 k1 = reinterpret_cast<const float4*>(Km + (size_t)d1 * 256)[lane];
        float p0 = q.x * k0.x + q.y * k0.y + q.z * k0.z + q.w * k0.w;
        float p1 = q.x * k1.x + q.y * k1.y + q.z * k1.z + q.w * k1.w;
        for (int st = 1; st < 16; st <<= 1) { p0 += __shfl_xor(p0, st); p1 += __shfl_xor(p1, st); }
        float s1a = p0 * scale, s1b = p1 * scale;
        float vd0 = vw[d0 * 4 + h], vd1 = vw[d1 * 4 + h];
        float m0 = fmaxf(s0, s1a), m1 = fmaxf(s0, s1b);
        float e00 = expf(s0 - m0), e01 = expf(s1a - m0);
        float e10 = expf(s0 - m1), e11 = expf(s1b - m1);
        float c0 = (e00 * vs + e01 * vd0) / (e00 + e01);
        float c1 = (e10 * vs + e11 * vd1) / (e10 + e11);
        c0 += __shfl_xor(c0, 16); c0 += __shfl_xor(c0, 32);
        c1 += __shfl_xor(c1, 16); c1 += __shfl_xor(c1, 32);
        if (lane == 0) {
            out[seid[i]]     = 1.f / (1.f + expf(-(c0 + bs)));
            out[seid[i + 1]] = 1.f / (1.f + expf(-(c1 + bs)));
        }
    }
    for (; i < end; ++i) {
        int d = sdst[i];
        float4 k = reinterpret_cast<const float4*>(Km + (size_t)d * 256)[lane];
        float p = q.x * k.x + q.y * k.y + q.z * k.z + q.w * k.w;
        for (int st = 1; st < 16; st <<= 1) p += __shfl_xor(p, st);
        float s1 = p * scale;
        float vd = vw[d * 4 + h];
        float m = fmaxf(s0, s1);
        float e0 = expf(s0 - m), e1 = expf(s1 - m);
        float c = (e0 * vs + e1 * vd) / (e0 + e1);
        c += __shfl_xor(c, 16); c += __shfl_xor(c, 32);
        if (lane == 0) out[seid[i]] = 1.f / (1.f + expf(-(c + bs)));
    }
}

extern "C" void kernel_launch(void* const* d_in, const int* in_sizes, int n_in,
                              void* d_out, int out_size, void* d_ws, size_t ws_size,
                              hipStream_t stream) {
    const float* x   = (const float*)d_in[0];
    const int*   ei  = (const int*)d_in[1];
    const int*   eip = (const int*)d_in[2];
    const float* W1  = (const float*)d_in[3];
    const float* b1  = (const float*)d_in[4];
    const float* W2  = (const float*)d_in[5];
    const float* b2  = (const float*)d_in[6];
    const float* ipw = (const float*)d_in[7];
    const float* ipb = (const float*)d_in[8];
    const float* opw = (const float*)d_in[9];
    const float* opb = (const float*)d_in[10];
    float* out = (float*)d_out;

    const int N = in_sizes[0] / IN_CH;      // 50000
    const int E = in_sizes[1] / 2;          // 1.6M
    const int EP = in_sizes[2] / 2;         // 500K

    // workspace layout (floats), 16B alignment for float4 arrays
    float* wsf = (float*)d_ws;
    size_t o = 0;
    auto pad4 = [&](size_t v) { return (v + 3) & ~(size_t)3; };
    int*   deg     = (int*)(wsf + o); o += pad4(N);
    float* dinv    = wsf + o; o += pad4(N);
    float* wsum    = wsf + o; o += 256;
    float* bsum    = wsf + o; o += 4;
    float* wv_eff  = wsf + o; o += 1024;
    float* vconst  = wsf + o; o += 4;
    float* Wqt     = wsf + o; o += 256 * 256;
    float* Wkt     = wsf + o; o += 256 * 256;
    float* qk_self = wsf + o; o += pad4((size_t)4 * N);
    float* vw      = wsf + o; o += pad4((size_t)4 * N);
    int*   offs    = (int*)(wsf + o); o += pad4((size_t)N + 1);
    int*   cursor  = (int*)(wsf + o); o += pad4(N);
    int*   part    = (int*)(wsf + o); o += 256;
    int*   ssrc    = (int*)(wsf + o); o += pad4(E);
    int*   deg_p   = (int*)(wsf + o); o += pad4(N);
    int*   offs_p  = (int*)(wsf + o); o += pad4((size_t)N + 1);
    int*   sdst    = (int*)(wsf + o); o += pad4(EP);
    int*   seid    = (int*)(wsf + o); o += pad4(EP);
    float* A       = wsf + o; o += (size_t)N * 256;
    float* B       = wsf + o; o += (size_t)N * 256;
    float* Cb      = wsf + o; o += (size_t)N * 256;
    (void)ws_size; (void)n_in; (void)out_size;

    const int* src = ei;
    const int* dst = ei + E;
    const int* sp  = eip;
    const int* dp  = eip + EP;
    const int nb = (N + 255) / 256;

    // ---- message-graph CSR (counting sort by dst) ----
    hipMemsetAsync(deg, 0, (size_t)N * 4, stream);
    hipMemsetAsync(cursor, 0, (size_t)N * 4, stream);
    hipMemsetAsync(deg_p, 0, (size_t)N * 4, stream);
    k_deg<<<(E + 255) / 256, 256, 0, stream>>>(dst, deg, E);
    k_dinv<<<nb, 256, 0, stream>>>(deg, dinv, N);
    k_chunksum<<<nb, 256, 0, stream>>>(deg, part, N);
    k_scanpart<<<1, 256, 0, stream>>>(part, nb);
    k_scanfinal<<<nb, 256, 0, stream>>>(deg, part, offs, N, E);
    k_scatter<<<(E + 255) / 256, 256, 0, stream>>>(src, dst, offs, cursor, ssrc, E);

    // ---- pred-edge CSR (counting sort by src, payload = dst + edge id) ----
    k_deg<<<(EP + 255) / 256, 256, 0, stream>>>(sp, deg_p, EP);
    k_chunksum<<<nb, 256, 0, stream>>>(deg_p, part, N);
    k_scanpart<<<1, 256, 0, stream>>>(part, nb);
    k_scanfinal<<<nb, 256, 0, stream>>>(deg_p, part, offs_p, N, EP);
    hipMemsetAsync(deg_p, 0, (size_t)N * 4, stream);   // reuse as cursor
    k_scatter2<<<(EP + 255) / 256, 256, 0, stream>>>(sp, dp, offs_p, deg_p, sdst, seid, EP);

    // small precomputes (independent of GCN)
    k_transpose256<<<256, 256, 0, stream>>>(ipw, Wqt);
    k_transpose256<<<256, 256, 0, stream>>>(ipw + 256 * 256, Wkt);
    k_wsum<<<1, 256, 0, stream>>>(opw, opb, wsum, bsum);
    k_wveff<<<4, 256, 0, stream>>>(ipw, ipb, wsum, wv_eff, vconst);

    const int gBlocks = (N + 63) / 64;
    const int aBlocks = (N + 3) / 4;

    // ---- layer 1 ----
    k_gemm64<128><<<gBlocks, 256, 0, stream>>>(x, W1, b1, dinv, A, N);
    k_gather_agg<<<aBlocks, 256, 0, stream>>>(A, offs, ssrc, dinv, B, N, 1);

    // ---- layer 2 ----
    k_gemm64<256><<<gBlocks, 256, 0, stream>>>(B, W2, b2, dinv, Cb, N);
    k_gather_agg<<<aBlocks, 256, 0, stream>>>(Cb, offs, ssrc, dinv, A, N, 0);

    // ---- attention precompute: B = Q, Cb = K ----
    k_gemm64<256><<<gBlocks, 256, 0, stream>>>(A, Wqt, ipb, nullptr, B, N);
    k_gemm64<256><<<gBlocks, 256, 0, stream>>>(A, Wkt, ipb + 256, nullptr, Cb, N);
    k_node_aux<<<aBlocks, 256, 0, stream>>>(B, Cb, A, wv_eff, vconst, qk_self, vw, N);

    // ---- per pred edge, grouped by source ----
    k_edge_pred_grouped<<<aBlocks, 256, 0, stream>>>(B, Cb, qk_self, vw, bsum,
                                                     offs_p, sdst, seid, out, N);
}

// Round 5
// 956.559 us; speedup vs baseline: 1.3087x; 1.3087x over previous
//
#include <hip/hip_runtime.h>
#include <hip/hip_bf16.h>

#define HIDDEN 256
#define IN_CH 128

__device__ inline float bf2f(unsigned short u) {
    union { unsigned int i; float f; } x; x.i = ((unsigned int)u) << 16; return x.f;
}
__device__ inline unsigned short f2bf(float f) {
    union { float f; unsigned int i; } x; x.f = f;
    unsigned int r = x.i + 0x7FFF + ((x.i >> 16) & 1);   // RNE
    return (unsigned short)(r >> 16);
}

// ---------------- degree (generic over an index array) ----------------
__global__ void k_deg(const int* __restrict__ idx, int* __restrict__ deg, int E) {
    int e = blockIdx.x * blockDim.x + threadIdx.x;
    if (e < E) atomicAdd(&deg[idx[e]], 1);
}

__global__ void k_dinv(const int* __restrict__ deg, float* __restrict__ dinv, int N) {
    int n = blockIdx.x * blockDim.x + threadIdx.x;
    if (n < N) dinv[n] = rsqrtf((float)deg[n] + 1.0f);  // +1 self loop
}

// ---------------- hierarchical exclusive prefix scan of deg -> offs ----------------
__global__ void k_chunksum(const int* __restrict__ deg, int* __restrict__ part, int N) {
    __shared__ int sh[256];
    int i = blockIdx.x * 256 + threadIdx.x;
    sh[threadIdx.x] = (i < N) ? deg[i] : 0;
    __syncthreads();
    for (int st = 128; st > 0; st >>= 1) {
        if (threadIdx.x < st) sh[threadIdx.x] += sh[threadIdx.x + st];
        __syncthreads();
    }
    if (threadIdx.x == 0) part[blockIdx.x] = sh[0];
}

__global__ void k_scanpart(int* __restrict__ part, int nb) {
    __shared__ int sh[256];
    int v = (threadIdx.x < nb) ? part[threadIdx.x] : 0;
    sh[threadIdx.x] = v;
    __syncthreads();
    for (int st = 1; st < 256; st <<= 1) {
        int t = (threadIdx.x >= st) ? sh[threadIdx.x - st] : 0;
        __syncthreads();
        sh[threadIdx.x] += t;
        __syncthreads();
    }
    if (threadIdx.x < nb) part[threadIdx.x] = sh[threadIdx.x] - v;
}

__global__ void k_scanfinal(const int* __restrict__ deg, const int* __restrict__ part,
                            int* __restrict__ offs, int N, int E) {
    __shared__ int sh[256];
    int i = blockIdx.x * 256 + threadIdx.x;
    int v = (i < N) ? deg[i] : 0;
    sh[threadIdx.x] = v;
    __syncthreads();
    for (int st = 1; st < 256; st <<= 1) {
        int t = (threadIdx.x >= st) ? sh[threadIdx.x - st] : 0;
        __syncthreads();
        sh[threadIdx.x] += t;
        __syncthreads();
    }
    if (i < N) offs[i] = part[blockIdx.x] + sh[threadIdx.x] - v;
    if (i == 0) offs[N] = E;
}

// ---------------- counting-sort scatters ----------------
__global__ void k_scatter(const int* __restrict__ pay, const int* __restrict__ key,
                          const int* __restrict__ offs, int* __restrict__ cursor,
                          int* __restrict__ spay, int E) {
    int e = blockIdx.x * blockDim.x + threadIdx.x;
    if (e >= E) return;
    int d = key[e];
    int p = offs[d] + atomicAdd(&cursor[d], 1);
    spay[p] = pay[e];
}

__global__ void k_scatter2(const int* __restrict__ key, const int* __restrict__ pay,
                           const int* __restrict__ offs, int* __restrict__ cursor,
                           int* __restrict__ spay, int* __restrict__ seid, int E) {
    int e = blockIdx.x * blockDim.x + threadIdx.x;
    if (e >= E) return;
    int s = key[e];
    int p = offs[s] + atomicAdd(&cursor[s], 1);
    spay[p] = pay[e];
    seid[p] = e;
}

// ---------------- a1[d] = dinv[d]*(sum_{s->d} dinv[s] + dinv[d]) ----------------
__global__ __launch_bounds__(256) void k_a1(const int* __restrict__ offs,
        const int* __restrict__ ssrc, const float* __restrict__ dinv,
        float* __restrict__ a1, int N) {
    int wid = threadIdx.x >> 6, lane = threadIdx.x & 63;
    int d = blockIdx.x * 4 + wid;
    if (d >= N) return;
    int beg = offs[d], end = offs[d + 1];
    float s = 0.f;
    for (int i = beg + lane; i < end; i += 64) s += dinv[ssrc[i]];
    for (int st = 1; st < 64; st <<= 1) s += __shfl_xor(s, st);
    if (lane == 0) a1[d] = dinv[d] * (s + dinv[d]);
}

// ---------------- Xs = dinv[row] * x  (128-dim rows) ----------------
__global__ void k_scale_x(const float* __restrict__ x, const float* __restrict__ dinv,
                          float* __restrict__ Xs, int n4) {
    int i = blockIdx.x * blockDim.x + threadIdx.x;   // float4 id, 32 per row
    if (i >= n4) return;
    float4 v = reinterpret_cast<const float4*>(x)[i];
    float s = dinv[i >> 5];
    v.x *= s; v.y *= s; v.z *= s; v.w *= s;
    reinterpret_cast<float4*>(Xs)[i] = v;
}

// ---------------- register-blocked GEMM: 64x256 tile ----------------
// C = act( A@W + bscale?*bias ) * rowscale?, optional bf16 output
template<int K, bool BF16OUT, bool RELU>
__global__ __launch_bounds__(256) void k_gemm64(const float* __restrict__ A,
        const float* __restrict__ W, const float* __restrict__ bias,
        const float* __restrict__ rowscale, const float* __restrict__ bscale,
        void* __restrict__ Cout, int M) {
    __shared__ float As[32 * 64];   // [k][m]
    __shared__ float Bs[32 * 256];  // [k][n]
    const int tid = threadIdx.x;
    const int tc = tid & 63;
    const int tr = tid >> 6;
    const int m0 = blockIdx.x * 64;
    const int rows = (M - m0 < 64) ? (M - m0) : 64;

    float acc[16][4];
#pragma unroll
    for (int r = 0; r < 16; ++r)
#pragma unroll
        for (int c = 0; c < 4; ++c) acc[r][c] = 0.f;

    const int arow = tid & 63;
    const int akq = tid >> 6;
    float4* As4 = reinterpret_cast<float4*>(As);
    float4* Bs4 = reinterpret_cast<float4*>(Bs);

    for (int kc = 0; kc < K; kc += 32) {
        __syncthreads();
#pragma unroll
        for (int it = 0; it < 2; ++it) {
            int kq = akq + it * 4;
            float4 v = make_float4(0.f, 0.f, 0.f, 0.f);
            if (arow < rows)
                v = *reinterpret_cast<const float4*>(A + (size_t)(m0 + arow) * K + kc + kq * 4);
            As[(kq * 4 + 0) * 64 + arow] = v.x;
            As[(kq * 4 + 1) * 64 + arow] = v.y;
            As[(kq * 4 + 2) * 64 + arow] = v.z;
            As[(kq * 4 + 3) * 64 + arow] = v.w;
        }
        const float4* W4 = reinterpret_cast<const float4*>(W + (size_t)kc * 256);
#pragma unroll
        for (int it = 0; it < 8; ++it)
            Bs4[tid + it * 256] = W4[tid + it * 256];
        __syncthreads();
#pragma unroll 8
        for (int kk = 0; kk < 32; ++kk) {
            float4 b = Bs4[kk * 64 + tc];
#pragma unroll
            for (int u = 0; u < 4; ++u) {
                float4 a = As4[kk * 16 + tr * 4 + u];
                acc[u * 4 + 0][0] = fmaf(a.x, b.x, acc[u * 4 + 0][0]);
                acc[u * 4 + 0][1] = fmaf(a.x, b.y, acc[u * 4 + 0][1]);
                acc[u * 4 + 0][2] = fmaf(a.x, b.z, acc[u * 4 + 0][2]);
                acc[u * 4 + 0][3] = fmaf(a.x, b.w, acc[u * 4 + 0][3]);
                acc[u * 4 + 1][0] = fmaf(a.y, b.x, acc[u * 4 + 1][0]);
                acc[u * 4 + 1][1] = fmaf(a.y, b.y, acc[u * 4 + 1][1]);
                acc[u * 4 + 1][2] = fmaf(a.y, b.z, acc[u * 4 + 1][2]);
                acc[u * 4 + 1][3] = fmaf(a.y, b.w, acc[u * 4 + 1][3]);
                acc[u * 4 + 2][0] = fmaf(a.z, b.x, acc[u * 4 + 2][0]);
                acc[u * 4 + 2][1] = fmaf(a.z, b.y, acc[u * 4 + 2][1]);
                acc[u * 4 + 2][2] = fmaf(a.z, b.z, acc[u * 4 + 2][2]);
                acc[u * 4 + 2][3] = fmaf(a.z, b.w, acc[u * 4 + 2][3]);
                acc[u * 4 + 3][0] = fmaf(a.w, b.x, acc[u * 4 + 3][0]);
                acc[u * 4 + 3][1] = fmaf(a.w, b.y, acc[u * 4 + 3][1]);
                acc[u * 4 + 3][2] = fmaf(a.w, b.z, acc[u * 4 + 3][2]);
                acc[u * 4 + 3][3] = fmaf(a.w, b.w, acc[u * 4 + 3][3]);
            }
        }
    }

    float4 bv = *reinterpret_cast<const float4*>(bias + tc * 4);
#pragma unroll
    for (int r = 0; r < 16; ++r) {
        int lrow = tr * 16 + r;
        if (lrow < rows) {
            float bsc = bscale ? bscale[m0 + lrow] : 1.f;
            float4 v;
            v.x = acc[r][0] + bsc * bv.x;
            v.y = acc[r][1] + bsc * bv.y;
            v.z = acc[r][2] + bsc * bv.z;
            v.w = acc[r][3] + bsc * bv.w;
            if (rowscale) {
                float s = rowscale[m0 + lrow];
                v.x *= s; v.y *= s; v.z *= s; v.w *= s;
            }
            if (RELU) {
                v.x = fmaxf(v.x, 0.f); v.y = fmaxf(v.y, 0.f);
                v.z = fmaxf(v.z, 0.f); v.w = fmaxf(v.w, 0.f);
            }
            if (BF16OUT) {
                ushort4 u;
                u.x = f2bf(v.x); u.y = f2bf(v.y); u.z = f2bf(v.z); u.w = f2bf(v.w);
                reinterpret_cast<ushort4*>((unsigned short*)Cout + (size_t)(m0 + lrow) * 256)[tc] = u;
            } else {
                reinterpret_cast<float4*>((float*)Cout + (size_t)(m0 + lrow) * 256)[tc] = v;
            }
        }
    }
}

// ---------------- gather aggregation, 128-dim f32 rows (layer 1, pre-GEMM) ----------------
__global__ __launch_bounds__(256) void k_gather128(const float* __restrict__ Xs,
        const int* __restrict__ offs, const int* __restrict__ ssrc,
        const float* __restrict__ dinv, float* __restrict__ outp, int N) {
    int wid = threadIdx.x >> 6, lane = threadIdx.x & 63;
    int d = blockIdx.x * 4 + wid;
    if (d >= N) return;
    int beg = offs[d], end = offs[d + 1];
    float2 acc = reinterpret_cast<const float2*>(Xs + (size_t)d * 128)[lane];  // self
    int i = beg;
    for (; i + 8 <= end; i += 8) {
        int s0 = ssrc[i], s1 = ssrc[i + 1], s2 = ssrc[i + 2], s3 = ssrc[i + 3];
        int s4 = ssrc[i + 4], s5 = ssrc[i + 5], s6 = ssrc[i + 6], s7 = ssrc[i + 7];
        float2 v0 = reinterpret_cast<const float2*>(Xs + (size_t)s0 * 128)[lane];
        float2 v1 = reinterpret_cast<const float2*>(Xs + (size_t)s1 * 128)[lane];
        float2 v2 = reinterpret_cast<const float2*>(Xs + (size_t)s2 * 128)[lane];
        float2 v3 = reinterpret_cast<const float2*>(Xs + (size_t)s3 * 128)[lane];
        float2 v4 = reinterpret_cast<const float2*>(Xs + (size_t)s4 * 128)[lane];
        float2 v5 = reinterpret_cast<const float2*>(Xs + (size_t)s5 * 128)[lane];
        float2 v6 = reinterpret_cast<const float2*>(Xs + (size_t)s6 * 128)[lane];
        float2 v7 = reinterpret_cast<const float2*>(Xs + (size_t)s7 * 128)[lane];
        acc.x += ((v0.x + v1.x) + (v2.x + v3.x)) + ((v4.x + v5.x) + (v6.x + v7.x));
        acc.y += ((v0.y + v1.y) + (v2.y + v3.y)) + ((v4.y + v5.y) + (v6.y + v7.y));
    }
    for (; i < end; ++i) {
        int s = ssrc[i];
        float2 v = reinterpret_cast<const float2*>(Xs + (size_t)s * 128)[lane];
        acc.x += v.x; acc.y += v.y;
    }
    float sc = dinv[d];
    acc.x *= sc; acc.y *= sc;
    reinterpret_cast<float2*>(outp + (size_t)d * 128)[lane] = acc;
}

// ---------------- gather aggregation, 256-dim bf16 rows -> f32 out (layer 2) ----------------
__global__ __launch_bounds__(256) void k_gather_bf16(const unsigned short* __restrict__ Ys,
        const int* __restrict__ offs, const int* __restrict__ ssrc,
        const float* __restrict__ dinv, float* __restrict__ outp, int N) {
    int wid = threadIdx.x >> 6, lane = threadIdx.x & 63;
    int d = blockIdx.x * 4 + wid;
    if (d >= N) return;
    int beg = offs[d], end = offs[d + 1];
    ushort4 sv = reinterpret_cast<const ushort4*>(Ys + (size_t)d * 256)[lane];
    float a0 = bf2f(sv.x), a1 = bf2f(sv.y), a2 = bf2f(sv.z), a3 = bf2f(sv.w);
    int i = beg;
    for (; i + 8 <= end; i += 8) {
        ushort4 v[8];
#pragma unroll
        for (int u = 0; u < 8; ++u)
            v[u] = reinterpret_cast<const ushort4*>(Ys + (size_t)ssrc[i + u] * 256)[lane];
#pragma unroll
        for (int u = 0; u < 8; ++u) {
            a0 += bf2f(v[u].x); a1 += bf2f(v[u].y);
            a2 += bf2f(v[u].z); a3 += bf2f(v[u].w);
        }
    }
    for (; i < end; ++i) {
        ushort4 v = reinterpret_cast<const ushort4*>(Ys + (size_t)ssrc[i] * 256)[lane];
        a0 += bf2f(v.x); a1 += bf2f(v.y); a2 += bf2f(v.z); a3 += bf2f(v.w);
    }
    float sc = dinv[d];
    float4 r = make_float4(a0 * sc, a1 * sc, a2 * sc, a3 * sc);
    reinterpret_cast<float4*>(outp + (size_t)d * 256)[lane] = r;
}

// ---------------- transpose 256x256 ----------------
__global__ void k_transpose256(const float* __restrict__ Win, float* __restrict__ Wout) {
    int j = threadIdx.x, k = blockIdx.x;
    Wout[k * 256 + j] = Win[j * 256 + k];
}

// ---------------- wsum / bsum ----------------
__global__ void k_wsum(const float* __restrict__ opw, const float* __restrict__ opb,
                       float* __restrict__ wsum, float* __restrict__ bsum) {
    int c = threadIdx.x;
    float s = 0.f;
    for (int j = 0; j < 256; ++j) s += opw[j * 256 + c];
    wsum[c] = s;
    __shared__ float red[256];
    red[c] = opb[c];
    __syncthreads();
    for (int st = 128; st > 0; st >>= 1) {
        if (c < st) red[c] += red[c + st];
        __syncthreads();
    }
    if (c == 0) *bsum = red[0];
}

// ---------------- wv_eff ----------------
__global__ void k_wveff(const float* __restrict__ ipw, const float* __restrict__ ipb,
                        const float* __restrict__ wsum, float* __restrict__ wv_eff,
                        float* __restrict__ vconst) {
    int h = blockIdx.x, k = threadIdx.x;
    float s = 0.f;
    for (int c = 0; c < 64; ++c)
        s += wsum[h * 64 + c] * ipw[(size_t)(512 + h * 64 + c) * 256 + k];
    wv_eff[h * 256 + k] = s;
    if (k == 0) {
        float t = 0.f;
        for (int c = 0; c < 64; ++c) t += ipb[512 + h * 64 + c] * wsum[h * 64 + c];
        vconst[h] = t;
    }
}

// ---------------- per-node: qk_self[n][h], vw[n][h]  (K in bf16) ----------------
__global__ void k_node_aux(const float* __restrict__ Q, const unsigned short* __restrict__ Km,
                           const float* __restrict__ Z, const float* __restrict__ wv_eff,
                           const float* __restrict__ vconst,
                           float* __restrict__ qk_self, float* __restrict__ vw, int N) {
    int wid = threadIdx.x >> 6, lane = threadIdx.x & 63;
    int n = blockIdx.x * 4 + wid;
    if (n >= N) return;
    float4 q = reinterpret_cast<const float4*>(Q + (size_t)n * 256)[lane];
    ushort4 ku = reinterpret_cast<const ushort4*>(Km + (size_t)n * 256)[lane];
    float4 z = reinterpret_cast<const float4*>(Z + (size_t)n * 256)[lane];
    float p = q.x * bf2f(ku.x) + q.y * bf2f(ku.y) + q.z * bf2f(ku.z) + q.w * bf2f(ku.w);
    for (int st = 1; st < 16; st <<= 1) p += __shfl_xor(p, st);
    if ((lane & 15) == 0) qk_self[n * 4 + (lane >> 4)] = p;

    float ph0, ph1, ph2, ph3;
    {
        float4 w;
        w = reinterpret_cast<const float4*>(wv_eff + 0 * 256)[lane];
        ph0 = z.x * w.x + z.y * w.y + z.z * w.z + z.w * w.w;
        w = reinterpret_cast<const float4*>(wv_eff + 1 * 256)[lane];
        ph1 = z.x * w.x + z.y * w.y + z.z * w.z + z.w * w.w;
        w = reinterpret_cast<const float4*>(wv_eff + 2 * 256)[lane];
        ph2 = z.x * w.x + z.y * w.y + z.z * w.z + z.w * w.w;
        w = reinterpret_cast<const float4*>(wv_eff + 3 * 256)[lane];
        ph3 = z.x * w.x + z.y * w.y + z.z * w.z + z.w * w.w;
    }
    for (int st = 1; st < 64; st <<= 1) {
        ph0 += __shfl_xor(ph0, st);
        ph1 += __shfl_xor(ph1, st);
        ph2 += __shfl_xor(ph2, st);
        ph3 += __shfl_xor(ph3, st);
    }
    if (lane == 0) {
        vw[n * 4 + 0] = ph0 + vconst[0];
        vw[n * 4 + 1] = ph1 + vconst[1];
        vw[n * 4 + 2] = ph2 + vconst[2];
        vw[n * 4 + 3] = ph3 + vconst[3];
    }
}

// ---------------- per pred-edge final, grouped by source (K in bf16) ----------------
__global__ __launch_bounds__(256) void k_edge_pred_grouped(const float* __restrict__ Q,
        const unsigned short* __restrict__ Km, const float* __restrict__ qk_self,
        const float* __restrict__ vw, const float* __restrict__ bsum,
        const int* __restrict__ offs_p, const int* __restrict__ sdst,
        const int* __restrict__ seid, float* __restrict__ out, int N) {
    int wid = threadIdx.x >> 6, lane = threadIdx.x & 63;
    int s = blockIdx.x * 4 + wid;
    if (s >= N) return;
    int beg = offs_p[s], end = offs_p[s + 1];
    if (beg == end) return;
    float4 q = reinterpret_cast<const float4*>(Q + (size_t)s * 256)[lane];
    int h = lane >> 4;
    const float scale = 0.125f;
    float s0 = qk_self[s * 4 + h] * scale;
    float vs = vw[s * 4 + h];
    float bs = *bsum;

    int i = beg;
    for (; i + 2 <= end; i += 2) {
        int d0 = sdst[i], d1 = sdst[i + 1];
        ushort4 k0 = reinterpret_cast<const ushort4*>(Km + (size_t)d0 * 256)[lane];
        ushort4 k1 = reinterpret_cast<const ushort4*>(Km + (size_t)d1 * 256)[lane];
        float p0 = q.x * bf2f(k0.x) + q.y * bf2f(k0.y) + q.z * bf2f(k0.z) + q.w * bf2f(k0.w);
        float p1 = q.x * bf2f(k1.x) + q.y * bf2f(k1.y) + q.z * bf2f(k1.z) + q.w * bf2f(k1.w);
        for (int st = 1; st < 16; st <<= 1) { p0 += __shfl_xor(p0, st); p1 += __shfl_xor(p1, st); }
        float s1a = p0 * scale, s1b = p1 * scale;
        float vd0 = vw[d0 * 4 + h], vd1 = vw[d1 * 4 + h];
        float m0 = fmaxf(s0, s1a), m1 = fmaxf(s0, s1b);
        float e00 = expf(s0 - m0), e01 = expf(s1a - m0);
        float e10 = expf(s0 - m1), e11 = expf(s1b - m1);
        float c0 = (e00 * vs + e01 * vd0) / (e00 + e01);
        float c1 = (e10 * vs + e11 * vd1) / (e10 + e11);
        c0 += __shfl_xor(c0, 16); c0 += __shfl_xor(c0, 32);
        c1 += __shfl_xor(c1, 16); c1 += __shfl_xor(c1, 32);
        if (lane == 0) {
            out[seid[i]]     = 1.f / (1.f + expf(-(c0 + bs)));
            out[seid[i + 1]] = 1.f / (1.f + expf(-(c1 + bs)));
        }
    }
    for (; i < end; ++i) {
        int d = sdst[i];
        ushort4 ku = reinterpret_cast<const ushort4*>(Km + (size_t)d * 256)[lane];
        float p = q.x * bf2f(ku.x) + q.y * bf2f(ku.y) + q.z * bf2f(ku.z) + q.w * bf2f(ku.w);
        for (int st = 1; st < 16; st <<= 1) p += __shfl_xor(p, st);
        float s1 = p * scale;
        float vd = vw[d * 4 + h];
        float m = fmaxf(s0, s1);
        float e0 = expf(s0 - m), e1 = expf(s1 - m);
        float c = (e0 * vs + e1 * vd) / (e0 + e1);
        c += __shfl_xor(c, 16); c += __shfl_xor(c, 32);
        if (lane == 0) out[seid[i]] = 1.f / (1.f + expf(-(c + bs)));
    }
}

extern "C" void kernel_launch(void* const* d_in, const int* in_sizes, int n_in,
                              void* d_out, int out_size, void* d_ws, size_t ws_size,
                              hipStream_t stream) {
    const float* x   = (const float*)d_in[0];
    const int*   ei  = (const int*)d_in[1];
    const int*   eip = (const int*)d_in[2];
    const float* W1  = (const float*)d_in[3];
    const float* b1  = (const float*)d_in[4];
    const float* W2  = (const float*)d_in[5];
    const float* b2  = (const float*)d_in[6];
    const float* ipw = (const float*)d_in[7];
    const float* ipb = (const float*)d_in[8];
    const float* opw = (const float*)d_in[9];
    const float* opb = (const float*)d_in[10];
    float* out = (float*)d_out;

    const int N = in_sizes[0] / IN_CH;      // 50000
    const int E = in_sizes[1] / 2;          // 1.6M
    const int EP = in_sizes[2] / 2;         // 500K

    // workspace layout (floats), 16B alignment for vector arrays
    float* wsf = (float*)d_ws;
    size_t o = 0;
    auto pad4 = [&](size_t v) { return (v + 3) & ~(size_t)3; };
    int*   deg     = (int*)(wsf + o); o += pad4(N);
    float* dinv    = wsf + o; o += pad4(N);
    float* a1v     = wsf + o; o += pad4(N);
    float* wsum    = wsf + o; o += 256;
    float* bsum    = wsf + o; o += 4;
    float* wv_eff  = wsf + o; o += 1024;
    float* vconst  = wsf + o; o += 4;
    float* Wqt     = wsf + o; o += 256 * 256;
    float* Wkt     = wsf + o; o += 256 * 256;
    float* qk_self = wsf + o; o += pad4((size_t)4 * N);
    float* vw      = wsf + o; o += pad4((size_t)4 * N);
    int*   offs    = (int*)(wsf + o); o += pad4((size_t)N + 1);
    int*   cursor  = (int*)(wsf + o); o += pad4(N);
    int*   part    = (int*)(wsf + o); o += 256;
    int*   ssrc    = (int*)(wsf + o); o += pad4(E);
    int*   deg_p   = (int*)(wsf + o); o += pad4(N);
    int*   offs_p  = (int*)(wsf + o); o += pad4((size_t)N + 1);
    int*   sdst    = (int*)(wsf + o); o += pad4(EP);
    int*   seid    = (int*)(wsf + o); o += pad4(EP);
    float* P1      = wsf + o; o += (size_t)N * 128;   // Xs; later Y2 bf16 (same bytes)
    float* P2      = wsf + o; o += (size_t)N * 128;   // aggx; later K bf16
    float* H       = wsf + o; o += (size_t)N * 256;   // h; later z
    float* Q       = wsf + o; o += (size_t)N * 256;   // Q f32
    (void)ws_size; (void)n_in; (void)out_size;

    unsigned short* Y2bf = (unsigned short*)P1;
    unsigned short* Kbf  = (unsigned short*)P2;
    float* Z = H;

    const int* src = ei;
    const int* dst = ei + E;
    const int* sp  = eip;
    const int* dp  = eip + EP;
    const int nb = (N + 255) / 256;

    // ---- message-graph CSR (counting sort by dst) ----
    hipMemsetAsync(deg, 0, (size_t)N * 4, stream);
    hipMemsetAsync(cursor, 0, (size_t)N * 4, stream);
    hipMemsetAsync(deg_p, 0, (size_t)N * 4, stream);
    k_deg<<<(E + 255) / 256, 256, 0, stream>>>(dst, deg, E);
    k_dinv<<<nb, 256, 0, stream>>>(deg, dinv, N);
    k_chunksum<<<nb, 256, 0, stream>>>(deg, part, N);
    k_scanpart<<<1, 256, 0, stream>>>(part, nb);
    k_scanfinal<<<nb, 256, 0, stream>>>(deg, part, offs, N, E);
    k_scatter<<<(E + 255) / 256, 256, 0, stream>>>(src, dst, offs, cursor, ssrc, E);

    const int aBlocks = (N + 3) / 4;
    k_a1<<<aBlocks, 256, 0, stream>>>(offs, ssrc, dinv, a1v, N);

    // ---- pred-edge CSR (counting sort by src, payload = dst + edge id) ----
    k_deg<<<(EP + 255) / 256, 256, 0, stream>>>(sp, deg_p, EP);
    k_chunksum<<<nb, 256, 0, stream>>>(deg_p, part, N);
    k_scanpart<<<1, 256, 0, stream>>>(part, nb);
    k_scanfinal<<<nb, 256, 0, stream>>>(deg_p, part, offs_p, N, EP);
    hipMemsetAsync(deg_p, 0, (size_t)N * 4, stream);   // reuse as cursor
    k_scatter2<<<(EP + 255) / 256, 256, 0, stream>>>(sp, dp, offs_p, deg_p, sdst, seid, EP);

    // small precomputes (independent of GCN)
    k_transpose256<<<256, 256, 0, stream>>>(ipw, Wqt);
    k_transpose256<<<256, 256, 0, stream>>>(ipw + 256 * 256, Wkt);
    k_wsum<<<1, 256, 0, stream>>>(opw, opb, wsum, bsum);
    k_wveff<<<4, 256, 0, stream>>>(ipw, ipb, wsum, wv_eff, vconst);

    const int gBlocks = (N + 63) / 64;

    // ---- layer 1 (aggregation commuted before GEMM, 128-dim) ----
    k_scale_x<<<(N * 32 + 255) / 256, 256, 0, stream>>>(x, dinv, P1, N * 32);
    k_gather128<<<aBlocks, 256, 0, stream>>>(P1, offs, ssrc, dinv, P2, N);
    // h = relu(aggx @ W1 + a1*b1)
    k_gemm64<128, false, true><<<gBlocks, 256, 0, stream>>>(P2, W1, b1, nullptr, a1v, H, N);

    // ---- layer 2: y2 = dinv*(h@W2+b2) in bf16; z = gather ----
    k_gemm64<256, true, false><<<gBlocks, 256, 0, stream>>>(H, W2, b2, dinv, nullptr, Y2bf, N);
    k_gather_bf16<<<aBlocks, 256, 0, stream>>>(Y2bf, offs, ssrc, dinv, Z, N);

    // ---- attention precompute: Q f32, K bf16 ----
    k_gemm64<256, false, false><<<gBlocks, 256, 0, stream>>>(Z, Wqt, ipb, nullptr, nullptr, Q, N);
    k_gemm64<256, true, false><<<gBlocks, 256, 0, stream>>>(Z, Wkt, ipb + 256, nullptr, nullptr, Kbf, N);
    k_node_aux<<<aBlocks, 256, 0, stream>>>(Q, Kbf, Z, wv_eff, vconst, qk_self, vw, N);

    // ---- per pred edge, grouped by source ----
    k_edge_pred_grouped<<<aBlocks, 256, 0, stream>>>(Q, Kbf, qk_self, vw, bsum,
                                                     offs_p, sdst, seid, out, N);
}

// Round 6
// 689.550 us; speedup vs baseline: 1.8155x; 1.3872x over previous
//
#include <hip/hip_runtime.h>
#include <hip/hip_bf16.h>

#define HIDDEN 256
#define IN_CH 128

typedef __attribute__((ext_vector_type(8))) short bf16x8;
typedef __attribute__((ext_vector_type(4))) float f32x4;

__device__ inline float bf2f(unsigned short u) {
    union { unsigned int i; float f; } x; x.i = ((unsigned int)u) << 16; return x.f;
}
__device__ inline unsigned short f2bf(float f) {
    union { float f; unsigned int i; } x; x.f = f;
    unsigned int r = x.i + 0x7FFF + ((x.i >> 16) & 1);   // RNE
    return (unsigned short)(r >> 16);
}

// ---------------- degree ----------------
__global__ void k_deg(const int* __restrict__ idx, int* __restrict__ deg, int E) {
    int e = blockIdx.x * blockDim.x + threadIdx.x;
    if (e < E) atomicAdd(&deg[idx[e]], 1);
}

__global__ void k_dinv(const int* __restrict__ deg, float* __restrict__ dinv, int N) {
    int n = blockIdx.x * blockDim.x + threadIdx.x;
    if (n < N) dinv[n] = rsqrtf((float)deg[n] + 1.0f);
}

// ---------------- prefix scan ----------------
__global__ void k_chunksum(const int* __restrict__ deg, int* __restrict__ part, int N) {
    __shared__ int sh[256];
    int i = blockIdx.x * 256 + threadIdx.x;
    sh[threadIdx.x] = (i < N) ? deg[i] : 0;
    __syncthreads();
    for (int st = 128; st > 0; st >>= 1) {
        if (threadIdx.x < st) sh[threadIdx.x] += sh[threadIdx.x + st];
        __syncthreads();
    }
    if (threadIdx.x == 0) part[blockIdx.x] = sh[0];
}

__global__ void k_scanpart(int* __restrict__ part, int nb) {
    __shared__ int sh[256];
    int v = (threadIdx.x < nb) ? part[threadIdx.x] : 0;
    sh[threadIdx.x] = v;
    __syncthreads();
    for (int st = 1; st < 256; st <<= 1) {
        int t = (threadIdx.x >= st) ? sh[threadIdx.x - st] : 0;
        __syncthreads();
        sh[threadIdx.x] += t;
        __syncthreads();
    }
    if (threadIdx.x < nb) part[threadIdx.x] = sh[threadIdx.x] - v;
}

__global__ void k_scanfinal(const int* __restrict__ deg, const int* __restrict__ part,
                            int* __restrict__ offs, int N, int E) {
    __shared__ int sh[256];
    int i = blockIdx.x * 256 + threadIdx.x;
    int v = (i < N) ? deg[i] : 0;
    sh[threadIdx.x] = v;
    __syncthreads();
    for (int st = 1; st < 256; st <<= 1) {
        int t = (threadIdx.x >= st) ? sh[threadIdx.x - st] : 0;
        __syncthreads();
        sh[threadIdx.x] += t;
        __syncthreads();
    }
    if (i < N) offs[i] = part[blockIdx.x] + sh[threadIdx.x] - v;
    if (i == 0) offs[N] = E;
}

// ---------------- counting-sort scatters ----------------
__global__ void k_scatter(const int* __restrict__ pay, const int* __restrict__ key,
                          const int* __restrict__ offs, int* __restrict__ cursor,
                          int* __restrict__ spay, int E) {
    int e = blockIdx.x * blockDim.x + threadIdx.x;
    if (e >= E) return;
    int d = key[e];
    int p = offs[d] + atomicAdd(&cursor[d], 1);
    spay[p] = pay[e];
}

__global__ void k_scatter2(const int* __restrict__ key, const int* __restrict__ pay,
                           const int* __restrict__ offs, int* __restrict__ cursor,
                           int* __restrict__ spay, int* __restrict__ seid, int E) {
    int e = blockIdx.x * blockDim.x + threadIdx.x;
    if (e >= E) return;
    int s = key[e];
    int p = offs[s] + atomicAdd(&cursor[s], 1);
    spay[p] = pay[e];
    seid[p] = e;
}

// ---------------- a1[d] = dinv[d]*(sum dinv[s] + dinv[d]) ----------------
__global__ __launch_bounds__(256) void k_a1(const int* __restrict__ offs,
        const int* __restrict__ ssrc, const float* __restrict__ dinv,
        float* __restrict__ a1, int N) {
    int wid = threadIdx.x >> 6, lane = threadIdx.x & 63;
    int d = blockIdx.x * 4 + wid;
    if (d >= N) return;
    int beg = offs[d], end = offs[d + 1];
    float s = 0.f;
    for (int i = beg + lane; i < end; i += 64) s += dinv[ssrc[i]];
    for (int st = 1; st < 64; st <<= 1) s += __shfl_xor(s, st);
    if (lane == 0) a1[d] = dinv[d] * (s + dinv[d]);
}

// ---------------- xb = bf16(dinv[row] * x)  (128-dim rows) ----------------
__global__ void k_scale_xb(const float* __restrict__ x, const float* __restrict__ dinv,
                           unsigned short* __restrict__ xb, int n4) {
    int i = blockIdx.x * blockDim.x + threadIdx.x;   // float4 id, 32 per row
    if (i >= n4) return;
    float4 v = reinterpret_cast<const float4*>(x)[i];
    float s = dinv[i >> 5];
    ushort4 u;
    u.x = f2bf(v.x * s); u.y = f2bf(v.y * s); u.z = f2bf(v.z * s); u.w = f2bf(v.w * s);
    reinterpret_cast<ushort4*>(xb)[i] = u;
}

// ---------------- weight fragment pack: Wf[kc32][ct][lane][8] bf16 ----------------
// W_eff[k][n] = src[k*sk + n*sn]
__global__ void k_wfrag(const float* __restrict__ src, unsigned short* __restrict__ wf,
                        int sk, int sn) {
    int b = blockIdx.x;          // kc32*16 + ct
    int ct = b & 15, kc32 = b >> 4;
    int l = threadIdx.x;         // 0..63
    int k0 = kc32 * 32 + (l >> 4) * 8;
    int n = ct * 16 + (l & 15);
    unsigned short* o = wf + ((size_t)b * 64 + l) * 8;
#pragma unroll
    for (int j = 0; j < 8; ++j)
        o[j] = f2bf(src[(size_t)(k0 + j) * sk + (size_t)n * sn]);
}

// ---------------- MFMA GEMM: C[M,256] = act((A@W + bscale?*bias) * rowscale?) ----------------
// A bf16 row-major [M][K]; Wf fragment-major; 1 wave = 16 rows, block = 4 waves.
template<int K, int BF16OUT, int RELU>
__global__ __launch_bounds__(256) void k_mgemm(const unsigned short* __restrict__ A,
        const unsigned short* __restrict__ Wf, const float* __restrict__ bias,
        const float* __restrict__ rowscale, const float* __restrict__ bscale,
        void* __restrict__ Cout, int M) {
    const int lane = threadIdx.x & 63;
    const int row0 = blockIdx.x * 64 + (threadIdx.x >> 6) * 16;
    if (row0 >= M) return;

    f32x4 acc[16];
#pragma unroll
    for (int ct = 0; ct < 16; ++ct) acc[ct] = (f32x4){0.f, 0.f, 0.f, 0.f};

    const unsigned short* arow = A + (size_t)(row0 + (lane & 15)) * K + (lane >> 4) * 8;
    const bf16x8* wbase = reinterpret_cast<const bf16x8*>(Wf) + lane;

#pragma unroll
    for (int kc = 0; kc < K; kc += 32) {
        bf16x8 a = *reinterpret_cast<const bf16x8*>(arow + kc);
        const bf16x8* wp = wbase + (size_t)(kc >> 5) * 1024;
#pragma unroll
        for (int ct = 0; ct < 16; ++ct)
            acc[ct] = __builtin_amdgcn_mfma_f32_16x16x32_bf16(a, wp[ct * 64], acc[ct], 0, 0, 0);
    }

    const int col0 = lane & 15;
    const int rsub = (lane >> 4) * 4;
    float bsc[4], rsc[4];
#pragma unroll
    for (int r = 0; r < 4; ++r) {
        int grow = row0 + rsub + r;
        bsc[r] = bscale ? bscale[grow] : 1.f;
        rsc[r] = rowscale ? rowscale[grow] : 1.f;
    }
#pragma unroll
    for (int ct = 0; ct < 16; ++ct) {
        int col = ct * 16 + col0;
        float bv = bias[col];
#pragma unroll
        for (int r = 0; r < 4; ++r) {
            int grow = row0 + rsub + r;
            float v = (acc[ct][r] + bsc[r] * bv) * rsc[r];
            if (RELU) v = fmaxf(v, 0.f);
            if (BF16OUT) ((unsigned short*)Cout)[(size_t)grow * 256 + col] = f2bf(v);
            else          ((float*)Cout)[(size_t)grow * 256 + col] = v;
        }
    }
}

// ---------------- gather, 128-dim bf16 rows -> bf16 out (layer 1, pre-GEMM) ----------------
__global__ __launch_bounds__(256) void k_gather128b(const unsigned short* __restrict__ Xs,
        const int* __restrict__ offs, const int* __restrict__ ssrc,
        const float* __restrict__ dinv, unsigned short* __restrict__ outp, int N) {
    int wid = threadIdx.x >> 6, lane = threadIdx.x & 63;
    int d = blockIdx.x * 4 + wid;
    if (d >= N) return;
    int beg = offs[d], end = offs[d + 1];
    ushort2 sv = reinterpret_cast<const ushort2*>(Xs + (size_t)d * 128)[lane];
    float a0 = bf2f(sv.x), a1 = bf2f(sv.y);
    int i = beg;
    for (; i + 8 <= end; i += 8) {
        ushort2 v[8];
#pragma unroll
        for (int u = 0; u < 8; ++u)
            v[u] = reinterpret_cast<const ushort2*>(Xs + (size_t)ssrc[i + u] * 128)[lane];
#pragma unroll
        for (int u = 0; u < 8; ++u) { a0 += bf2f(v[u].x); a1 += bf2f(v[u].y); }
    }
    for (; i < end; ++i) {
        ushort2 v = reinterpret_cast<const ushort2*>(Xs + (size_t)ssrc[i] * 128)[lane];
        a0 += bf2f(v.x); a1 += bf2f(v.y);
    }
    float sc = dinv[d];
    ushort2 r; r.x = f2bf(a0 * sc); r.y = f2bf(a1 * sc);
    reinterpret_cast<ushort2*>(outp + (size_t)d * 128)[lane] = r;
}

// ---------------- gather, 256-dim bf16 rows -> bf16 out (layer 2) ----------------
__global__ __launch_bounds__(256) void k_gather256b(const unsigned short* __restrict__ Ys,
        const int* __restrict__ offs, const int* __restrict__ ssrc,
        const float* __restrict__ dinv, unsigned short* __restrict__ outp, int N) {
    int wid = threadIdx.x >> 6, lane = threadIdx.x & 63;
    int d = blockIdx.x * 4 + wid;
    if (d >= N) return;
    int beg = offs[d], end = offs[d + 1];
    ushort4 sv = reinterpret_cast<const ushort4*>(Ys + (size_t)d * 256)[lane];
    float a0 = bf2f(sv.x), a1 = bf2f(sv.y), a2 = bf2f(sv.z), a3 = bf2f(sv.w);
    int i = beg;
    for (; i + 8 <= end; i += 8) {
        ushort4 v[8];
#pragma unroll
        for (int u = 0; u < 8; ++u)
            v[u] = reinterpret_cast<const ushort4*>(Ys + (size_t)ssrc[i + u] * 256)[lane];
#pragma unroll
        for (int u = 0; u < 8; ++u) {
            a0 += bf2f(v[u].x); a1 += bf2f(v[u].y);
            a2 += bf2f(v[u].z); a3 += bf2f(v[u].w);
        }
    }
    for (; i < end; ++i) {
        ushort4 v = reinterpret_cast<const ushort4*>(Ys + (size_t)ssrc[i] * 256)[lane];
        a0 += bf2f(v.x); a1 += bf2f(v.y); a2 += bf2f(v.z); a3 += bf2f(v.w);
    }
    float sc = dinv[d];
    ushort4 r;
    r.x = f2bf(a0 * sc); r.y = f2bf(a1 * sc); r.z = f2bf(a2 * sc); r.w = f2bf(a3 * sc);
    reinterpret_cast<ushort4*>(outp + (size_t)d * 256)[lane] = r;
}

// ---------------- wsum / bsum ----------------
__global__ void k_wsum(const float* __restrict__ opw, const float* __restrict__ opb,
                       float* __restrict__ wsum, float* __restrict__ bsum) {
    int c = threadIdx.x;
    float s = 0.f;
    for (int j = 0; j < 256; ++j) s += opw[j * 256 + c];
    wsum[c] = s;
    __shared__ float red[256];
    red[c] = opb[c];
    __syncthreads();
    for (int st = 128; st > 0; st >>= 1) {
        if (c < st) red[c] += red[c + st];
        __syncthreads();
    }
    if (c == 0) *bsum = red[0];
}

// ---------------- wv_eff ----------------
__global__ void k_wveff(const float* __restrict__ ipw, const float* __restrict__ ipb,
                        const float* __restrict__ wsum, float* __restrict__ wv_eff,
                        float* __restrict__ vconst) {
    int h = blockIdx.x, k = threadIdx.x;
    float s = 0.f;
    for (int c = 0; c < 64; ++c)
        s += wsum[h * 64 + c] * ipw[(size_t)(512 + h * 64 + c) * 256 + k];
    wv_eff[h * 256 + k] = s;
    if (k == 0) {
        float t = 0.f;
        for (int c = 0; c < 64; ++c) t += ipb[512 + h * 64 + c] * wsum[h * 64 + c];
        vconst[h] = t;
    }
}

// ---------------- per-node: qk_self[n][h], vw[n][h]  (K, z in bf16) ----------------
__global__ void k_node_aux(const float* __restrict__ Q, const unsigned short* __restrict__ Km,
                           const unsigned short* __restrict__ Zb, const float* __restrict__ wv_eff,
                           const float* __restrict__ vconst,
                           float* __restrict__ qk_self, float* __restrict__ vw, int N) {
    int wid = threadIdx.x >> 6, lane = threadIdx.x & 63;
    int n = blockIdx.x * 4 + wid;
    if (n >= N) return;
    float4 q = reinterpret_cast<const float4*>(Q + (size_t)n * 256)[lane];
    ushort4 ku = reinterpret_cast<const ushort4*>(Km + (size_t)n * 256)[lane];
    ushort4 zu = reinterpret_cast<const ushort4*>(Zb + (size_t)n * 256)[lane];
    float z0 = bf2f(zu.x), z1 = bf2f(zu.y), z2 = bf2f(zu.z), z3 = bf2f(zu.w);
    float p = q.x * bf2f(ku.x) + q.y * bf2f(ku.y) + q.z * bf2f(ku.z) + q.w * bf2f(ku.w);
    for (int st = 1; st < 16; st <<= 1) p += __shfl_xor(p, st);
    if ((lane & 15) == 0) qk_self[n * 4 + (lane >> 4)] = p;

    float ph0, ph1, ph2, ph3;
    {
        float4 w;
        w = reinterpret_cast<const float4*>(wv_eff + 0 * 256)[lane];
        ph0 = z0 * w.x + z1 * w.y + z2 * w.z + z3 * w.w;
        w = reinterpret_cast<const float4*>(wv_eff + 1 * 256)[lane];
        ph1 = z0 * w.x + z1 * w.y + z2 * w.z + z3 * w.w;
        w = reinterpret_cast<const float4*>(wv_eff + 2 * 256)[lane];
        ph2 = z0 * w.x + z1 * w.y + z2 * w.z + z3 * w.w;
        w = reinterpret_cast<const float4*>(wv_eff + 3 * 256)[lane];
        ph3 = z0 * w.x + z1 * w.y + z2 * w.z + z3 * w.w;
    }
    for (int st = 1; st < 64; st <<= 1) {
        ph0 += __shfl_xor(ph0, st);
        ph1 += __shfl_xor(ph1, st);
        ph2 += __shfl_xor(ph2, st);
        ph3 += __shfl_xor(ph3, st);
    }
    if (lane == 0) {
        vw[n * 4 + 0] = ph0 + vconst[0];
        vw[n * 4 + 1] = ph1 + vconst[1];
        vw[n * 4 + 2] = ph2 + vconst[2];
        vw[n * 4 + 3] = ph3 + vconst[3];
    }
}

// ---------------- per pred-edge final, grouped by source (K bf16) ----------------
__global__ __launch_bounds__(256) void k_edge_pred_grouped(const float* __restrict__ Q,
        const unsigned short* __restrict__ Km, const float* __restrict__ qk_self,
        const float* __restrict__ vw, const float* __restrict__ bsum,
        const int* __restrict__ offs_p, const int* __restrict__ sdst,
        const int* __restrict__ seid, float* __restrict__ out, int N) {
    int wid = threadIdx.x >> 6, lane = threadIdx.x & 63;
    int s = blockIdx.x * 4 + wid;
    if (s >= N) return;
    int beg = offs_p[s], end = offs_p[s + 1];
    if (beg == end) return;
    float4 q = reinterpret_cast<const float4*>(Q + (size_t)s * 256)[lane];
    int h = lane >> 4;
    const float scale = 0.125f;
    float s0 = qk_self[s * 4 + h] * scale;
    float vs = vw[s * 4 + h];
    float bs = *bsum;

    int i = beg;
    for (; i + 2 <= end; i += 2) {
        int d0 = sdst[i], d1 = sdst[i + 1];
        ushort4 k0 = reinterpret_cast<const ushort4*>(Km + (size_t)d0 * 256)[lane];
        ushort4 k1 = reinterpret_cast<const ushort4*>(Km + (size_t)d1 * 256)[lane];
        float p0 = q.x * bf2f(k0.x) + q.y * bf2f(k0.y) + q.z * bf2f(k0.z) + q.w * bf2f(k0.w);
        float p1 = q.x * bf2f(k1.x) + q.y * bf2f(k1.y) + q.z * bf2f(k1.z) + q.w * bf2f(k1.w);
        for (int st = 1; st < 16; st <<= 1) { p0 += __shfl_xor(p0, st); p1 += __shfl_xor(p1, st); }
        float s1a = p0 * scale, s1b = p1 * scale;
        float vd0 = vw[d0 * 4 + h], vd1 = vw[d1 * 4 + h];
        float m0 = fmaxf(s0, s1a), m1 = fmaxf(s0, s1b);
        float e00 = expf(s0 - m0), e01 = expf(s1a - m0);
        float e10 = expf(s0 - m1), e11 = expf(s1b - m1);
        float c0 = (e00 * vs + e01 * vd0) / (e00 + e01);
        float c1 = (e10 * vs + e11 * vd1) / (e10 + e11);
        c0 += __shfl_xor(c0, 16); c0 += __shfl_xor(c0, 32);
        c1 += __shfl_xor(c1, 16); c1 += __shfl_xor(c1, 32);
        if (lane == 0) {
            out[seid[i]]     = 1.f / (1.f + expf(-(c0 + bs)));
            out[seid[i + 1]] = 1.f / (1.f + expf(-(c1 + bs)));
        }
    }
    for (; i < end; ++i) {
        int d = sdst[i];
        ushort4 ku = reinterpret_cast<const ushort4*>(Km + (size_t)d * 256)[lane];
        float p = q.x * bf2f(ku.x) + q.y * bf2f(ku.y) + q.z * bf2f(ku.z) + q.w * bf2f(ku.w);
        for (int st = 1; st < 16; st <<= 1) p += __shfl_xor(p, st);
        float s1 = p * scale;
        float vd = vw[d * 4 + h];
        float m = fmaxf(s0, s1);
        float e0 = expf(s0 - m), e1 = expf(s1 - m);
        float c = (e0 * vs + e1 * vd) / (e0 + e1);
        c += __shfl_xor(c, 16); c += __shfl_xor(c, 32);
        if (lane == 0) out[seid[i]] = 1.f / (1.f + expf(-(c + bs)));
    }
}

extern "C" void kernel_launch(void* const* d_in, const int* in_sizes, int n_in,
                              void* d_out, int out_size, void* d_ws, size_t ws_size,
                              hipStream_t stream) {
    const float* x   = (const float*)d_in[0];
    const int*   ei  = (const int*)d_in[1];
    const int*   eip = (const int*)d_in[2];
    const float* W1  = (const float*)d_in[3];
    const float* b1  = (const float*)d_in[4];
    const float* W2  = (const float*)d_in[5];
    const float* b2  = (const float*)d_in[6];
    const float* ipw = (const float*)d_in[7];
    const float* ipb = (const float*)d_in[8];
    const float* opw = (const float*)d_in[9];
    const float* opb = (const float*)d_in[10];
    float* out = (float*)d_out;

    const int N = in_sizes[0] / IN_CH;      // 50000
    const int E = in_sizes[1] / 2;          // 1.6M
    const int EP = in_sizes[2] / 2;         // 500K

    float* wsf = (float*)d_ws;
    size_t o = 0;
    auto pad4 = [&](size_t v) { return (v + 3) & ~(size_t)3; };
    int*   deg     = (int*)(wsf + o); o += pad4(N);
    float* dinv    = wsf + o; o += pad4(N);
    float* a1v     = wsf + o; o += pad4(N);
    float* wsum    = wsf + o; o += 256;
    float* bsum    = wsf + o; o += 4;
    float* wv_eff  = wsf + o; o += 1024;
    float* vconst  = wsf + o; o += 4;
    unsigned short* wf1 = (unsigned short*)(wsf + o); o += 16384;  // K=128 frags
    unsigned short* wf2 = (unsigned short*)(wsf + o); o += 32768;  // K=256
    unsigned short* wfq = (unsigned short*)(wsf + o); o += 32768;
    unsigned short* wfk = (unsigned short*)(wsf + o); o += 32768;
    float* qk_self = wsf + o; o += pad4((size_t)4 * N);
    float* vw      = wsf + o; o += pad4((size_t)4 * N);
    int*   offs    = (int*)(wsf + o); o += pad4((size_t)N + 1);
    int*   cursor  = (int*)(wsf + o); o += pad4(N);
    int*   part    = (int*)(wsf + o); o += 256;
    int*   ssrc    = (int*)(wsf + o); o += pad4(E);
    int*   deg_p   = (int*)(wsf + o); o += pad4(N);
    int*   offs_p  = (int*)(wsf + o); o += pad4((size_t)N + 1);
    int*   sdst    = (int*)(wsf + o); o += pad4(EP);
    int*   seid    = (int*)(wsf + o); o += pad4(EP);
    float* B1      = wsf + o; o += (size_t)N * 128;   // xb (half) -> y2
    float* B2      = wsf + o; o += (size_t)N * 128;   // aggx (half) -> z
    float* B3      = wsf + o; o += (size_t)N * 128;   // h -> Kb
    float* Q       = wsf + o; o += (size_t)N * 256;   // Q f32
    (void)ws_size; (void)n_in; (void)out_size;

    unsigned short* xb   = (unsigned short*)B1;
    unsigned short* y2   = (unsigned short*)B1;
    unsigned short* aggx = (unsigned short*)B2;
    unsigned short* zb   = (unsigned short*)B2;
    unsigned short* hb   = (unsigned short*)B3;
    unsigned short* kb   = (unsigned short*)B3;

    const int* src = ei;
    const int* dst = ei + E;
    const int* sp  = eip;
    const int* dp  = eip + EP;
    const int nb = (N + 255) / 256;
    const int aBlocks = (N + 3) / 4;
    const int gBlocks = (N + 63) / 64;

    // ---- message-graph CSR ----
    hipMemsetAsync(deg, 0, (size_t)N * 4, stream);
    hipMemsetAsync(cursor, 0, (size_t)N * 4, stream);
    hipMemsetAsync(deg_p, 0, (size_t)N * 4, stream);
    k_deg<<<(E + 255) / 256, 256, 0, stream>>>(dst, deg, E);
    k_dinv<<<nb, 256, 0, stream>>>(deg, dinv, N);
    k_chunksum<<<nb, 256, 0, stream>>>(deg, part, N);
    k_scanpart<<<1, 256, 0, stream>>>(part, nb);
    k_scanfinal<<<nb, 256, 0, stream>>>(deg, part, offs, N, E);
    k_scatter<<<(E + 255) / 256, 256, 0, stream>>>(src, dst, offs, cursor, ssrc, E);
    k_a1<<<aBlocks, 256, 0, stream>>>(offs, ssrc, dinv, a1v, N);

    // ---- pred-edge CSR ----
    k_deg<<<(EP + 255) / 256, 256, 0, stream>>>(sp, deg_p, EP);
    k_chunksum<<<nb, 256, 0, stream>>>(deg_p, part, N);
    k_scanpart<<<1, 256, 0, stream>>>(part, nb);
    k_scanfinal<<<nb, 256, 0, stream>>>(deg_p, part, offs_p, N, EP);
    hipMemsetAsync(deg_p, 0, (size_t)N * 4, stream);
    k_scatter2<<<(EP + 255) / 256, 256, 0, stream>>>(sp, dp, offs_p, deg_p, sdst, seid, EP);

    // ---- weight fragment packs + attention precomputes ----
    k_wfrag<<<4 * 16, 64, 0, stream>>>(W1, wf1, 256, 1);            // W1 [128][256]
    k_wfrag<<<8 * 16, 64, 0, stream>>>(W2, wf2, 256, 1);            // W2 [256][256]
    k_wfrag<<<8 * 16, 64, 0, stream>>>(ipw, wfq, 1, 256);           // Wq = ipw[0:256].T
    k_wfrag<<<8 * 16, 64, 0, stream>>>(ipw + 65536, wfk, 1, 256);   // Wk
    k_wsum<<<1, 256, 0, stream>>>(opw, opb, wsum, bsum);
    k_wveff<<<4, 256, 0, stream>>>(ipw, ipb, wsum, wv_eff, vconst);

    // ---- layer 1: aggregate x (commuted), then MFMA GEMM ----
    k_scale_xb<<<(N * 32 + 255) / 256, 256, 0, stream>>>(x, dinv, xb, N * 32);
    k_gather128b<<<aBlocks, 256, 0, stream>>>(xb, offs, ssrc, dinv, aggx, N);
    // h = relu(aggx @ W1 + a1*b1), bf16 out
    k_mgemm<128, 1, 1><<<gBlocks, 256, 0, stream>>>(aggx, wf1, b1, nullptr, a1v, hb, N);

    // ---- layer 2: y2 = dinv*(h@W2+b2) bf16; z = gather ----
    k_mgemm<256, 1, 0><<<gBlocks, 256, 0, stream>>>(hb, wf2, b2, dinv, nullptr, y2, N);
    k_gather256b<<<aBlocks, 256, 0, stream>>>(y2, offs, ssrc, dinv, zb, N);

    // ---- attention: Q f32, K bf16 ----
    k_mgemm<256, 0, 0><<<gBlocks, 256, 0, stream>>>(zb, wfq, ipb, nullptr, nullptr, Q, N);
    k_mgemm<256, 1, 0><<<gBlocks, 256, 0, stream>>>(zb, wfk, ipb + 256, nullptr, nullptr, kb, N);
    k_node_aux<<<aBlocks, 256, 0, stream>>>(Q, kb, zb, wv_eff, vconst, qk_self, vw, N);

    // ---- per pred edge, grouped by source ----
    k_edge_pred_grouped<<<aBlocks, 256, 0, stream>>>(Q, kb, qk_self, vw, bsum,
                                                     offs_p, sdst, seid, out, N);
}